// Round 1
// baseline (210.865 us; speedup 1.0000x reference)
//
#include <hip/hip_runtime.h>
#include <math.h>

#define NPROJ 16
#define NBINS 65536
#define WD (NBINS - 6)
#define B_ 2
#define C_ 3
#define H_ 384
#define W_ 384
#define HO 378
#define NPAT (HO * HO)            // 142884
#define DF (C_ * 7 * 7)           // 147
#define BP (B_ * NPROJ)           // 32

// ---------- float <-> monotone-unsigned key (for atomic min/max on floats) ----
__device__ inline unsigned f2key(float f) {
    unsigned u = __float_as_uint(f);
    return (u & 0x80000000u) ? ~u : (u | 0x80000000u);
}
__device__ inline float key2f(unsigned k) {
    unsigned u = (k & 0x80000000u) ? (k ^ 0x80000000u) : ~k;
    return __uint_as_float(u);
}

// ---------- K0: r = rand / std(rand, axis=d, ddof=1) --------------------------
__global__ __launch_bounds__(64) void k_rnorm(const float* __restrict__ rnd,
                                              float* __restrict__ rnorm) {
    int bp = blockIdx.x;               // b*NPROJ + p
    int b = bp / NPROJ, p = bp % NPROJ;
    int lane = threadIdx.x;
    float s = 0.f, s2 = 0.f;
    for (int d = lane; d < DF; d += 64) {
        float v = rnd[((size_t)b * DF + d) * NPROJ + p];
        s += v; s2 += v * v;
    }
    for (int o = 32; o > 0; o >>= 1) { s += __shfl_down(s, o); s2 += __shfl_down(s2, o); }
    s = __shfl(s, 0); s2 = __shfl(s2, 0);
    float mean = s / (float)DF;
    float var = (s2 - (float)DF * mean * mean) / (float)(DF - 1);
    float inv = 1.0f / sqrtf(var);
    for (int d = lane; d < DF; d += 64) {
        size_t idx = ((size_t)b * DF + d) * NPROJ + p;
        rnorm[idx] = rnd[idx] * inv;
    }
}

// ---------- K_init: min/max keys + loss accumulators --------------------------
__global__ void k_init(unsigned* keys, float* loss) {
    int i = threadIdx.x;
    if (i < BP) {
        keys[2 * i] = 0xFFFFFFFFu;  // min key
        keys[2 * i + 1] = 0u;       // max key
        loss[i] = 0.f;
    }
}

// ---------- K1: patch projection (7x7x3 conv, 16 outputs) ---------------------
// grid: (12, 12, 2*B_)  block: 256.  blockIdx.z: bit0 = which image, rest = b.
__global__ __launch_bounds__(256) void k_proj(const float* __restrict__ ximg,
                                              const float* __restrict__ yimg,
                                              const float* __restrict__ rnorm,
                                              float* __restrict__ proj_x,
                                              float* __restrict__ proj_y) {
    const int TILE = 32;
    __shared__ float tile[C_][TILE + 6][TILE + 6];
    __shared__ float wlds[DF][NPROJ];
    int bz = blockIdx.z;
    int b = bz >> 1;
    const float* img = (bz & 1) ? yimg : ximg;
    float* proj = (bz & 1) ? proj_y : proj_x;
    int tid = threadIdx.x;

    for (int i = tid; i < DF * NPROJ; i += 256)
        ((float*)wlds)[i] = rnorm[(size_t)b * DF * NPROJ + i];

    int h0 = blockIdx.y * TILE, w0 = blockIdx.x * TILE;
    for (int c = 0; c < C_; c++)
        for (int i = tid; i < (TILE + 6) * (TILE + 6); i += 256) {
            int r = i / (TILE + 6), col = i % (TILE + 6);
            int h = h0 + r, w = w0 + col;
            tile[c][r][col] = (h < H_ && w < W_)
                ? img[((size_t)(b * C_ + c) * H_ + h) * W_ + w] : 0.f;
        }
    __syncthreads();

    int tx = tid & 31, ty = tid >> 5;   // ty in 0..7, 4 pixel rows per thread
    float acc[4][NPROJ];
#pragma unroll
    for (int q = 0; q < 4; q++)
#pragma unroll
        for (int p = 0; p < NPROJ; p++) acc[q][p] = 0.f;

    for (int c = 0; c < C_; c++)
        for (int i = 0; i < 7; i++)
            for (int j = 0; j < 7; j++) {
                const float* wp = &wlds[c * 49 + i * 7 + j][0];
                float wv[NPROJ];
#pragma unroll
                for (int p = 0; p < NPROJ; p++) wv[p] = wp[p];
#pragma unroll
                for (int q = 0; q < 4; q++) {
                    float pix = tile[c][ty + 8 * q + i][tx + j];
#pragma unroll
                    for (int p = 0; p < NPROJ; p++)
                        acc[q][p] = fmaf(pix, wv[p], acc[q][p]);
                }
            }

#pragma unroll
    for (int q = 0; q < 4; q++) {
        int ho = h0 + ty + 8 * q, wo = w0 + tx;
        if (ho < HO && wo < HO) {
            size_t n = (size_t)ho * HO + wo;
#pragma unroll
            for (int p = 0; p < NPROJ; p++)
                proj[((size_t)(b * NPROJ + p)) * NPAT + n] = acc[q][p];
        }
    }
}

// ---------- K2: per-(b,p) min/max over both proj arrays ----------------------
__global__ __launch_bounds__(256) void k_minmax(const float* __restrict__ px,
                                                const float* __restrict__ py,
                                                unsigned* __restrict__ keys) {
    int bp = blockIdx.y;
    const float* a = px + (size_t)bp * NPAT;
    const float* b = py + (size_t)bp * NPAT;
    float mn = INFINITY, mx = -INFINITY;
    for (int i = blockIdx.x * blockDim.x + threadIdx.x; i < NPAT;
         i += gridDim.x * blockDim.x) {
        float v1 = a[i], v2 = b[i];
        mn = fminf(mn, fminf(v1, v2));
        mx = fmaxf(mx, fmaxf(v1, v2));
    }
    for (int o = 32; o > 0; o >>= 1) {
        mn = fminf(mn, __shfl_down(mn, o));
        mx = fmaxf(mx, __shfl_down(mx, o));
    }
    __shared__ float smn[4], smx[4];
    int wv = threadIdx.x >> 6;
    if ((threadIdx.x & 63) == 0) { smn[wv] = mn; smx[wv] = mx; }
    __syncthreads();
    if (threadIdx.x == 0) {
        for (int w = 1; w < 4; w++) { mn = fminf(mn, smn[w]); mx = fmaxf(mx, smx[w]); }
        atomicMin(&keys[2 * bp], f2key(mn));
        atomicMax(&keys[2 * bp + 1], f2key(mx));
    }
}

// ---------- K3: scatter-set 1.0 into histogram (idempotent, no atomics) ------
__global__ __launch_bounds__(256) void k_scatter(const float* __restrict__ py,
                                                 const unsigned* __restrict__ keys,
                                                 float* __restrict__ hist) {
    int bp = blockIdx.y;
    float mn = key2f(keys[2 * bp]);
    float mx = key2f(keys[2 * bp + 1]);
    float scale = mx - mn;
    const float* src = py + (size_t)bp * NPAT;
    float* h = hist + (size_t)bp * NBINS;
    for (int i = blockIdx.x * blockDim.x + threadIdx.x; i < NPAT;
         i += gridDim.x * blockDim.x) {
        float v = src[i];
        int idx = (int)floorf((float)(NBINS - 1) * (v - mn) / scale);
        idx = min(max(idx, 0), NBINS - 1);
        h[idx] = 1.0f;
    }
}

// ---------- K4: 7-tap gaussian smooth + clamp at 1.0 -------------------------
__global__ __launch_bounds__(256) void k_conv(const float* __restrict__ hist,
                                              float* __restrict__ smooth) {
    int bp = blockIdx.y;
    int w = blockIdx.x * blockDim.x + threadIdx.x;
    if (w >= WD) return;
    const float* h = hist + (size_t)bp * NBINS;
    float s = 0.f;
#pragma unroll
    for (int k = 0; k < 7; k++) {
        float d = (float)(k - 3);
        // reference: exp((x)^2 / (-2*1.2^2)) ** 2  == exp(-x^2/1.44)
        float g = expf(-d * d / 1.44f);
        s += h[w + k] * g;
    }
    smooth[(size_t)bp * WD + w] = fminf(s, 1.0f);
}

// ---------- K5: bilinear gather + per-(b,p) sum ------------------------------
__global__ __launch_bounds__(256) void k_gather(const float* __restrict__ px,
                                                const unsigned* __restrict__ keys,
                                                const float* __restrict__ smooth,
                                                float* __restrict__ loss) {
    int bp = blockIdx.y;
    float mn = key2f(keys[2 * bp]);
    float mx = key2f(keys[2 * bp + 1]);
    float scale = mx - mn;
    const float* src = px + (size_t)bp * NPAT;
    const float* sm = smooth + (size_t)bp * WD;
    float acc = 0.f;
    for (int i = blockIdx.x * blockDim.x + threadIdx.x; i < NPAT;
         i += gridDim.x * blockDim.x) {
        float t = (src[i] - mn) / scale;
        float ix = t * (float)WD - 0.5f;
        float x0 = floorf(ix);
        float w1 = ix - x0;
        int x0i = (int)x0;
        int x1i = x0i + 1;
        float v0 = (x0i >= 0 && x0i < WD) ? sm[x0i] : 0.f;
        float v1 = (x1i >= 0 && x1i < WD) ? sm[x1i] : 0.f;
        acc += v0 * (1.f - w1) + v1 * w1;
    }
    for (int o = 32; o > 0; o >>= 1) acc += __shfl_down(acc, o);
    __shared__ float sacc[4];
    int wv = threadIdx.x >> 6;
    if ((threadIdx.x & 63) == 0) sacc[wv] = acc;
    __syncthreads();
    if (threadIdx.x == 0) {
        float t = sacc[0] + sacc[1] + sacc[2] + sacc[3];
        atomicAdd(&loss[bp], t);
    }
}

// ---------- K6: finalize -----------------------------------------------------
__global__ void k_final(const float* __restrict__ loss, float* __restrict__ out) {
    float s = 0.f;
    for (int i = 0; i < BP; i++) s += loss[i];
    out[0] = -s / (float)(B_ * NPROJ);
}

extern "C" void kernel_launch(void* const* d_in, const int* in_sizes, int n_in,
                              void* d_out, int out_size, void* d_ws, size_t ws_size,
                              hipStream_t stream) {
    (void)in_sizes; (void)n_in; (void)out_size; (void)ws_size;
    const float* x = (const float*)d_in[0];
    const float* y = (const float*)d_in[1];
    const float* rnd = (const float*)d_in[2];
    float* out = (float*)d_out;

    float* ws = (float*)d_ws;
    float* rnorm = ws;                                     // 4704
    float* px = rnorm + (size_t)B_ * DF * NPROJ;           // BP*NPAT
    float* py = px + (size_t)BP * NPAT;                    // BP*NPAT
    unsigned* keys = (unsigned*)(py + (size_t)BP * NPAT);  // 2*BP uints
    float* loss = (float*)(keys + 2 * BP);                 // BP
    float* hist = loss + BP;                               // BP*NBINS
    float* smooth = hist + (size_t)BP * NBINS;             // BP*WD

    k_rnorm<<<BP, 64, 0, stream>>>(rnd, rnorm);
    k_init<<<1, 64, 0, stream>>>(keys, loss);

    dim3 pgrid((HO + 31) / 32, (HO + 31) / 32, 2 * B_);
    k_proj<<<pgrid, 256, 0, stream>>>(x, y, rnorm, px, py);

    hipMemsetAsync(hist, 0, (size_t)BP * NBINS * sizeof(float), stream);

    k_minmax<<<dim3(128, BP), 256, 0, stream>>>(px, py, keys);
    k_scatter<<<dim3(128, BP), 256, 0, stream>>>(py, keys, hist);
    k_conv<<<dim3((WD + 255) / 256, BP), 256, 0, stream>>>(hist, smooth);
    k_gather<<<dim3(128, BP), 256, 0, stream>>>(px, keys, smooth, loss);
    k_final<<<1, 1, 0, stream>>>(loss, out);
}